// Round 1
// baseline (319.945 us; speedup 1.0000x reference)
//
#include <hip/hip_runtime.h>
#include <math.h>

#define NPTS   12800
#define P_PIX  2560
#define NC     64          // compositing chunks (NPTS/NC = 200 pts/chunk)
#define CHUNK  200
#define RANK_CHUNK 800

// ---------------------------------------------------------------- init
__global__ __launch_bounds__(256) void init_kernel(int* rnk, float* out, int n) {
    int i = blockIdx.x * 256 + threadIdx.x;
    if (i < n) rnk[i] = 0;
    if (i == 0) out[0] = 0.0f;
}

// ---------------------------------------------------------------- transpose weights
__global__ __launch_bounds__(256) void transpose_kernel(
    const float* __restrict__ W1, const float* __restrict__ W2, const float* __restrict__ W3,
    float* __restrict__ W1T, float* __restrict__ W2T, float* __restrict__ W3T) {
    int idx = blockIdx.x * 256 + threadIdx.x;
    if (idx < 16384) {               // W1 (64,256) -> W1T (256,64)
        int j = idx >> 8, k = idx & 255;
        W1T[k * 64 + j] = W1[idx];
    } else if (idx < 16384 + 4096) { // W2 (64,64) -> W2T (64,64)
        int t = idx - 16384; int j = t >> 6, k = t & 63;
        W2T[k * 64 + j] = W2[t];
    } else if (idx < 16384 + 4096 + 1088) { // W3 (17,64) -> W3T (64,17)
        int t = idx - 20480; int c = t >> 6, k = t & 63;
        W3T[k * 17 + c] = W3[t];
    }
}

// ---------------------------------------------------------------- per-point projection
__global__ __launch_bounds__(256) void prep_kernel(
    const float* __restrict__ xyz, const float* __restrict__ scales,
    const float* __restrict__ rots, const float* __restrict__ opacity,
    const float* __restrict__ viewmat, const float* __restrict__ intrins,
    unsigned long long* __restrict__ keys,
    float* __restrict__ pu, float* __restrict__ pv, float* __restrict__ phA,
    float* __restrict__ phC, float* __restrict__ pnB, float* __restrict__ pop, int N) {
    int cam = blockIdx.y;
    int i = blockIdx.x * 256 + threadIdx.x;
    if (i >= N) return;
    const float* vm = viewmat + cam * 16;
    const float* it = intrins + cam * 4;
    float fx = it[0], fy = it[1], cx = it[2], cy = it[3];
    float R00 = vm[0], R01 = vm[1], R02 = vm[2], t0 = vm[3];
    float R10 = vm[4], R11 = vm[5], R12 = vm[6], t1 = vm[7];
    float R20 = vm[8], R21 = vm[9], R22 = vm[10], t2 = vm[11];
    float X = xyz[i * 3], Y = xyz[i * 3 + 1], Z = xyz[i * 3 + 2];
    float x = R00 * X + R01 * Y + R02 * Z + t0;
    float y = R10 * X + R11 * Y + R12 * Z + t1;
    float z = R20 * X + R21 * Y + R22 * Z + t2;
    float zc = fmaxf(z, 0.001f);
    float iz = 1.0f / zc;
    float u = fx * x * iz + cx;
    float v = fy * y * iz + cy;
    // normalized quaternion -> rotation
    float qw = rots[i * 4], qx = rots[i * 4 + 1], qy = rots[i * 4 + 2], qz = rots[i * 4 + 3];
    float qn = 1.0f / sqrtf(qw * qw + qx * qx + qy * qy + qz * qz);
    qw *= qn; qx *= qn; qy *= qn; qz *= qn;
    float s0 = expf(scales[i * 3]), s1 = expf(scales[i * 3 + 1]), s2 = expf(scales[i * 3 + 2]);
    float Rq[3][3] = {
        {1 - 2 * (qy * qy + qz * qz), 2 * (qx * qy - qw * qz), 2 * (qx * qz + qw * qy)},
        {2 * (qx * qy + qw * qz), 1 - 2 * (qx * qx + qz * qz), 2 * (qy * qz - qw * qx)},
        {2 * (qx * qz - qw * qy), 2 * (qy * qz + qw * qx), 1 - 2 * (qx * qx + qy * qy)}};
    float M[3][3];
    #pragma unroll
    for (int r = 0; r < 3; ++r) { M[r][0] = Rq[r][0] * s0; M[r][1] = Rq[r][1] * s1; M[r][2] = Rq[r][2] * s2; }
    float c3[3][3];
    #pragma unroll
    for (int a = 0; a < 3; ++a)
        #pragma unroll
        for (int b = 0; b < 3; ++b)
            c3[a][b] = M[a][0] * M[b][0] + M[a][1] * M[b][1] + M[a][2] * M[b][2];
    float Rw[3][3] = {{R00, R01, R02}, {R10, R11, R12}, {R20, R21, R22}};
    float Wt[3][3];
    #pragma unroll
    for (int a = 0; a < 3; ++a)
        #pragma unroll
        for (int b = 0; b < 3; ++b)
            Wt[a][b] = Rw[a][0] * c3[0][b] + Rw[a][1] * c3[1][b] + Rw[a][2] * c3[2][b];
    float cw[3][3];
    #pragma unroll
    for (int a = 0; a < 3; ++a)
        #pragma unroll
        for (int b = 0; b < 3; ++b)
            cw[a][b] = Wt[a][0] * Rw[b][0] + Wt[a][1] * Rw[b][1] + Wt[a][2] * Rw[b][2];
    float j00 = fx * iz, j02 = -fx * x * iz * iz;
    float j11 = fy * iz, j12 = -fy * y * iz * iz;
    float c00 = j00 * j00 * cw[0][0] + 2.0f * j00 * j02 * cw[0][2] + j02 * j02 * cw[2][2];
    float c01 = j00 * j11 * cw[0][1] + j00 * j12 * cw[0][2] + j02 * j11 * cw[2][1] + j02 * j12 * cw[2][2];
    float c11 = j11 * j11 * cw[1][1] + 2.0f * j11 * j12 * cw[1][2] + j12 * j12 * cw[2][2];
    float a = c00 + 0.3f, bq = c01, cc = c11 + 0.3f;
    float det = a * cc - bq * bq;
    float A = cc / det, Bc = -bq / det, Cc = a / det;
    int idx = cam * N + i;
    pu[idx] = u; pv[idx] = v;
    phA[idx] = -0.5f * A; phC[idx] = -0.5f * Cc; pnB[idx] = -Bc;
    pop[idx] = (z > 0.2f) ? opacity[i] : 0.0f;
    unsigned int zb = __float_as_uint(z);
    zb = (zb & 0x80000000u) ? ~zb : (zb | 0x80000000u);
    keys[idx] = ((unsigned long long)zb << 32) | (unsigned int)i;
}

// ---------------------------------------------------------------- stable rank (= argsort position)
__global__ __launch_bounds__(256) void rank_kernel(const unsigned long long* __restrict__ keys,
                                                   int* __restrict__ rnk, int N) {
    __shared__ unsigned long long sk[RANK_CHUNK];
    int cam = blockIdx.z;
    const unsigned long long* K = keys + (size_t)cam * N;
    int jbase = blockIdx.y * RANK_CHUNK;
    int jcnt = min(RANK_CHUNK, N - jbase);
    for (int t = threadIdx.x; t < jcnt; t += 256) sk[t] = K[jbase + t];
    __syncthreads();
    int i = blockIdx.x * 256 + threadIdx.x;
    if (i >= N) return;
    unsigned long long ki = K[i];
    int cnt = 0;
    #pragma unroll 8
    for (int j = 0; j < jcnt; ++j) cnt += (sk[j] < ki) ? 1 : 0;
    if (cnt) atomicAdd(rnk + (size_t)cam * N + i, cnt);
}

// ---------------------------------------------------------------- scatter into sorted 24-float records
__global__ __launch_bounds__(256) void scatter_kernel(
    const int* __restrict__ rnk,
    const float* __restrict__ pu, const float* __restrict__ pv, const float* __restrict__ phA,
    const float* __restrict__ phC, const float* __restrict__ pnB, const float* __restrict__ pop,
    const float* __restrict__ feats, float* __restrict__ rec, int N) {
    int cam = blockIdx.y;
    int i = blockIdx.x * 256 + threadIdx.x;
    if (i >= N) return;
    int idx = cam * N + i;
    int r = rnk[idx];
    float* d = rec + ((size_t)cam * N + r) * 24;
    d[0] = pu[idx]; d[1] = pv[idx]; d[2] = phA[idx];
    d[3] = phC[idx]; d[4] = pnB[idx]; d[5] = pop[idx];
    const float* f = feats + (size_t)i * 17;
    #pragma unroll
    for (int c = 0; c < 17; ++c) d[6 + c] = f[c];
    d[23] = 0.0f;
}

// ---------------------------------------------------------------- chunked alpha compositing
__global__ __launch_bounds__(256) void splat_kernel(const float* __restrict__ rec,
                                                    float* __restrict__ part, int N) {
    __shared__ __align__(16) float srec[CHUNK * 24];
    int cam = blockIdx.z, ch = blockIdx.y;
    int p = blockIdx.x * 256 + threadIdx.x;
    float px = (float)(p & 63), py = (float)(p >> 6);
    const float4* src = (const float4*)(rec + ((size_t)cam * N + ch * CHUNK) * 24);
    float4* dst = (float4*)srec;
    for (int t = threadIdx.x; t < CHUNK * 6; t += 256) dst[t] = src[t];
    __syncthreads();
    float T = 1.0f;
    float acc[17];
    #pragma unroll
    for (int c = 0; c < 17; ++c) acc[c] = 0.0f;
    for (int n = 0; n < CHUNK; ++n) {
        const float* rp = srec + n * 24;
        float4 q0 = *(const float4*)(rp);        // u, v, hA, hC
        float4 q1 = *(const float4*)(rp + 4);    // nB, op, f0, f1
        float4 q2 = *(const float4*)(rp + 8);    // f2..f5
        float4 q3 = *(const float4*)(rp + 12);   // f6..f9
        float4 q4 = *(const float4*)(rp + 16);   // f10..f13
        float4 q5 = *(const float4*)(rp + 20);   // f14,f15,f16,pad
        float dx = q0.x - px, dy = q0.y - py;
        float t1 = (q0.z * dx) * dx;
        t1 = fmaf(q0.w * dy, dy, t1);
        float power = fmaf(q1.x * dx, dy, t1);
        power = fminf(power, 0.0f);
        float alpha = fminf(0.99f, q1.y * __expf(power));
        float w = alpha * T;
        acc[0]  = fmaf(w, q1.z, acc[0]);  acc[1]  = fmaf(w, q1.w, acc[1]);
        acc[2]  = fmaf(w, q2.x, acc[2]);  acc[3]  = fmaf(w, q2.y, acc[3]);
        acc[4]  = fmaf(w, q2.z, acc[4]);  acc[5]  = fmaf(w, q2.w, acc[5]);
        acc[6]  = fmaf(w, q3.x, acc[6]);  acc[7]  = fmaf(w, q3.y, acc[7]);
        acc[8]  = fmaf(w, q3.z, acc[8]);  acc[9]  = fmaf(w, q3.w, acc[9]);
        acc[10] = fmaf(w, q4.x, acc[10]); acc[11] = fmaf(w, q4.y, acc[11]);
        acc[12] = fmaf(w, q4.z, acc[12]); acc[13] = fmaf(w, q4.w, acc[13]);
        acc[14] = fmaf(w, q5.x, acc[14]); acc[15] = fmaf(w, q5.y, acc[15]);
        acc[16] = fmaf(w, q5.z, acc[16]);
        T *= (1.0f - alpha);
    }
    size_t base = ((size_t)(cam * NC + ch) * 18) * P_PIX + p;
    part[base] = T;
    #pragma unroll
    for (int c = 0; c < 17; ++c) part[base + (size_t)(1 + c) * P_PIX] = acc[c];
}

// ---------------------------------------------------------------- per-pixel transmittance prefix
__global__ __launch_bounds__(256) void tpref_kernel(const float* __restrict__ part,
                                                    float* __restrict__ tpref) {
    int cam = blockIdx.y;
    int p = blockIdx.x * 256 + threadIdx.x;
    float T = 1.0f;
    #pragma unroll 8
    for (int k = 0; k < NC; ++k) {
        tpref[((size_t)(cam * NC + k)) * P_PIX + p] = T;
        T *= part[((size_t)(cam * NC + k) * 18) * P_PIX + p];
    }
}

// ---------------------------------------------------------------- combine chunks -> fmap
__global__ __launch_bounds__(256) void combine_kernel(const float* __restrict__ part,
                                                      const float* __restrict__ tpref,
                                                      float* __restrict__ fmap) {
    int idx = blockIdx.x * 256 + threadIdx.x;
    if (idx >= 2 * 17 * P_PIX) return;
    int p = idx % P_PIX;
    int rem = idx / P_PIX;
    int c = rem % 17;
    int cam = rem / 17;
    float acc = 0.0f;
    #pragma unroll 8
    for (int k = 0; k < NC; ++k) {
        float Tp = tpref[((size_t)(cam * NC + k)) * P_PIX + p];
        float S = part[(((size_t)(cam * NC + k)) * 18 + 1 + c) * P_PIX + p];
        acc = fmaf(Tp, S, acc);
    }
    fmap[((size_t)cam * 17 + c) * P_PIX + p] = acc;
}

// ---------------------------------------------------------------- MLP (wave per row)
__global__ __launch_bounds__(256) void mlp_kernel(
    const float* __restrict__ embd, const float* __restrict__ sfeat,
    const float* __restrict__ W1T, const float* __restrict__ b1,
    const float* __restrict__ g1, const float* __restrict__ be1,
    const float* __restrict__ W2T, const float* __restrict__ b2,
    const float* __restrict__ g2, const float* __restrict__ be2,
    const float* __restrict__ W3T, const float* __restrict__ b3,
    float* __restrict__ sed, float* __restrict__ ldf) {
    __shared__ float sW2[4096];
    __shared__ float sW3[1088];
    for (int t = threadIdx.x; t < 4096; t += 256) sW2[t] = W2T[t];
    for (int t = threadIdx.x; t < 1088; t += 256) sW3[t] = W3T[t];
    __syncthreads();
    int lane = threadIdx.x & 63;
    int gw = (blockIdx.x * 256 + threadIdx.x) >> 6;  // global wave 0..4095
    const int NW = 4096;
    float b1l = b1[lane], g1l = g1[lane], be1l = be1[lane];
    float b2l = b2[lane], g2l = g2[lane], be2l = be2[lane];
    int c17 = lane < 17 ? lane : 16;
    float b3l = b3[c17];
    for (int row = gw; row < 13312; row += NW) {
        const float* xb;
        if (row < 5120) {  // sed rows: (cam, pixel)
            int cam = row / 2560; int p = row - cam * 2560;
            int r = p >> 6, xc = p & 63;
            int ri = (r * 8) / 5;  // == floor(r * 64/40), exact
            xb = embd + ((size_t)cam * 256) * 4096 + ri * 64 + xc;
        } else {           // ldf rows: (cam, t)
            int rr = row - 5120;
            int cam = rr >> 12; int t = rr & 4095;
            xb = sfeat + ((size_t)cam * 256) * 4096 + t;
        }
        // layer 1: 256 -> 64 (lane owns output feature `lane`)
        float a0 = 0, a1 = 0, a2 = 0, a3 = 0;
        for (int k = 0; k < 256; k += 4) {
            float x0 = xb[(size_t)k * 4096];
            float x1 = xb[(size_t)(k + 1) * 4096];
            float x2 = xb[(size_t)(k + 2) * 4096];
            float x3 = xb[(size_t)(k + 3) * 4096];
            a0 = fmaf(x0, W1T[(k) * 64 + lane], a0);
            a1 = fmaf(x1, W1T[(k + 1) * 64 + lane], a1);
            a2 = fmaf(x2, W1T[(k + 2) * 64 + lane], a2);
            a3 = fmaf(x3, W1T[(k + 3) * 64 + lane], a3);
        }
        float h = ((a0 + a1) + (a2 + a3)) + b1l;
        // LN1 across 64 lanes
        float s = h;
        #pragma unroll
        for (int o = 32; o; o >>= 1) s += __shfl_xor(s, o);
        float mu = s * (1.0f / 64.0f);
        float d = h - mu;
        float vs = d * d;
        #pragma unroll
        for (int o = 32; o; o >>= 1) vs += __shfl_xor(vs, o);
        float hn = d * (1.0f / sqrtf(vs * (1.0f / 64.0f) + 1e-5f)) * g1l + be1l;
        hn = fmaxf(hn, 0.01f * hn);
        // layer 2: 64 -> 64
        float a = 0;
        #pragma unroll 8
        for (int k = 0; k < 64; ++k)
            a = fmaf(__shfl(hn, k), sW2[k * 64 + lane], a);
        float h2 = a + b2l;
        s = h2;
        #pragma unroll
        for (int o = 32; o; o >>= 1) s += __shfl_xor(s, o);
        float mu2 = s * (1.0f / 64.0f);
        float d2 = h2 - mu2;
        float vs2 = d2 * d2;
        #pragma unroll
        for (int o = 32; o; o >>= 1) vs2 += __shfl_xor(vs2, o);
        float hn2 = d2 * (1.0f / sqrtf(vs2 * (1.0f / 64.0f) + 1e-5f)) * g2l + be2l;
        hn2 = fmaxf(hn2, 0.01f * hn2);
        // layer 3: 64 -> 17
        float a3o = 0;
        #pragma unroll 8
        for (int k = 0; k < 64; ++k)
            a3o = fmaf(__shfl(hn2, k), sW3[k * 17 + c17], a3o);
        float outv = a3o + b3l;
        if (lane < 17) {
            if (row < 5120) {
                int cam = row / 2560; int p = row - cam * 2560;
                sed[((size_t)cam * 2560 + p) * 17 + lane] = outv;
            } else {
                int rr = row - 5120; int cam = rr >> 12; int t = rr & 4095;
                ldf[((size_t)cam * 17 + lane) * 4096 + t] = outv;
            }
        }
    }
}

// ---------------------------------------------------------------- mask prototypes
__global__ __launch_bounds__(256) void proto_kernel(const float* __restrict__ masks,
                                                    const float* __restrict__ ldf,
                                                    float* __restrict__ proto) {
    int cam = blockIdx.y, m = blockIdx.x;
    const float* M = masks + ((size_t)cam * 16 + m) * 40000;
    float acc[18];
    #pragma unroll
    for (int j = 0; j < 18; ++j) acc[j] = 0.0f;
    for (int t = threadIdx.x; t < 4096; t += 256) {
        int h = t >> 6, w = t & 63;
        int rh = (h * 25) >> 3, rw = (w * 25) >> 3;  // == floor(*200/64), exact
        float lv = M[rh * 200 + rw];
        if (lv != 0.0f) {
            acc[17] += lv;
            const float* L = ldf + (size_t)cam * 17 * 4096 + t;
            #pragma unroll
            for (int c = 0; c < 17; ++c) acc[c] = fmaf(lv, L[(size_t)c * 4096], acc[c]);
        }
    }
    __shared__ float red[4][18];
    int lane = threadIdx.x & 63, wv = threadIdx.x >> 6;
    #pragma unroll
    for (int j = 0; j < 18; ++j) {
        float v = acc[j];
        #pragma unroll
        for (int o = 32; o; o >>= 1) v += __shfl_xor(v, o);
        if (lane == 0) red[wv][j] = v;
    }
    __syncthreads();
    if (threadIdx.x < 17) {
        float sacc = red[0][threadIdx.x] + red[1][threadIdx.x] + red[2][threadIdx.x] + red[3][threadIdx.x];
        float ms = red[0][17] + red[1][17] + red[2][17] + red[3][17];
        proto[((size_t)cam * 16 + m) * 17 + threadIdx.x] = sacc / fmaxf(ms, 1e-6f);
    }
}

__device__ __forceinline__ void block_atomic_add(float v, float* target) {
    #pragma unroll
    for (int o = 32; o; o >>= 1) v += __shfl_xor(v, o);
    __shared__ float sred[4];
    int lane = threadIdx.x & 63, wv = threadIdx.x >> 6;
    if (lane == 0) sred[wv] = v;
    __syncthreads();
    if (threadIdx.x == 0) atomicAdd(target, sred[0] + sred[1] + sred[2] + sred[3]);
}

// ---------------------------------------------------------------- BCE loss
__global__ __launch_bounds__(256) void bce_kernel(const float* __restrict__ masks,
                                                  const float* __restrict__ proto,
                                                  const float* __restrict__ fmap,
                                                  float* __restrict__ out) {
    int idx = blockIdx.x * 256 + threadIdx.x;  // < 2*16*2560
    int p = idx % P_PIX;
    int rem = idx / P_PIX;
    int m = rem & 15, cam = rem >> 4;
    const float* pr = proto + ((size_t)cam * 16 + m) * 17;
    float sdot = 0;
    #pragma unroll
    for (int c = 0; c < 17; ++c)
        sdot = fmaf(pr[c], fmap[((size_t)cam * 17 + c) * P_PIX + p], sdot);
    float prob = 1.0f / (1.0f + expf(-sdot));
    int px = p & 63, py = p >> 6;
    float src_r = (py + 0.5f) * 5.0f - 0.5f;     // 200/40
    float src_c = (px + 0.5f) * 3.125f - 0.5f;   // 200/64
    int r0 = (int)fminf(fmaxf(floorf(src_r), 0.0f), 199.0f);
    int r1 = min(r0 + 1, 199);
    float wr = fminf(fmaxf(src_r - (float)r0, 0.0f), 1.0f);
    int c0 = (int)fminf(fmaxf(floorf(src_c), 0.0f), 199.0f);
    int c1 = min(c0 + 1, 199);
    float wc = fminf(fmaxf(src_c - (float)c0, 0.0f), 1.0f);
    const float* M = masks + ((size_t)cam * 16 + m) * 40000;
    float v00 = M[r0 * 200 + c0], v01 = M[r0 * 200 + c1];
    float v10 = M[r1 * 200 + c0], v11 = M[r1 * 200 + c1];
    float xr0 = v00 * (1.0f - wr) + v10 * wr;
    float xr1 = v01 * (1.0f - wr) + v11 * wr;
    float frm = xr0 * (1.0f - wc) + xr1 * wc;
    frm = (frm <= 0.5f) ? 0.0f : frm;
    float bce = frm * logf(prob + 1e-8f) + (1.0f - frm) * logf(1.0f - prob + 1e-8f);
    block_atomic_add(bce * (-1.0f / (16.0f * 2560.0f * 2.0f)), out);
}

// ---------------------------------------------------------------- L1 loss
__global__ __launch_bounds__(256) void l1_kernel(const float* __restrict__ fmap,
                                                 const float* __restrict__ sed,
                                                 float* __restrict__ out) {
    int idx = blockIdx.x * 256 + threadIdx.x;  // < 2*2560
    float ssum = 0;
    if (idx < 2 * P_PIX) {
        int p = idx % P_PIX, cam = idx / P_PIX;
        #pragma unroll
        for (int c = 0; c < 17; ++c) {
            float dv = fmap[((size_t)cam * 17 + c) * P_PIX + p] - sed[((size_t)cam * P_PIX + p) * 17 + c];
            ssum += fabsf(dv);
        }
    }
    block_atomic_add(ssum * (1.0f / (43520.0f * 2.0f)), out);
}

// ================================================================ launch
extern "C" void kernel_launch(void* const* d_in, const int* in_sizes, int n_in,
                              void* d_out, int out_size, void* d_ws, size_t ws_size,
                              hipStream_t stream) {
    const float* voxel_feats = (const float*)d_in[0];
    const float* opacity     = (const float*)d_in[1];
    const float* sam_embd    = (const float*)d_in[2];
    const float* sam_features= (const float*)d_in[3];
    const float* sam_masks   = (const float*)d_in[4];
    const float* viewmat     = (const float*)d_in[5];
    const float* intrins     = (const float*)d_in[6];
    const float* pc_xyz      = (const float*)d_in[7];
    const float* scales      = (const float*)d_in[8];
    const float* rots        = (const float*)d_in[9];
    const float* W1 = (const float*)d_in[10], *b1 = (const float*)d_in[11];
    const float* g1 = (const float*)d_in[12], *be1 = (const float*)d_in[13];
    const float* W2 = (const float*)d_in[14], *b2 = (const float*)d_in[15];
    const float* g2 = (const float*)d_in[16], *be2 = (const float*)d_in[17];
    const float* W3 = (const float*)d_in[18], *b3 = (const float*)d_in[19];
    float* out = (float*)d_out;
    const int N = in_sizes[7] / 3;  // 12800

    char* w = (char*)d_ws;
    size_t off = 0;
    auto alloc = [&](size_t bytes) -> void* {
        off = (off + 255) & ~(size_t)255;
        void* p = w + off; off += bytes; return p;
    };
    int* rnk  = (int*)alloc((size_t)2 * N * sizeof(int));
    unsigned long long* keys = (unsigned long long*)alloc((size_t)2 * N * 8);
    float* params = (float*)alloc((size_t)6 * 2 * N * 4);
    float* pu = params,          *pv  = params + 2 * N, *phA = params + 4 * N;
    float* phC = params + 6 * N, *pnB = params + 8 * N, *pop = params + 10 * N;
    float* rec   = (float*)alloc((size_t)2 * N * 24 * 4);
    float* part  = (float*)alloc((size_t)2 * NC * 18 * P_PIX * 4);
    float* tpref = (float*)alloc((size_t)2 * NC * P_PIX * 4);
    float* fmap  = (float*)alloc((size_t)2 * 17 * P_PIX * 4);
    float* sed   = (float*)alloc((size_t)2 * P_PIX * 17 * 4);
    float* ldf   = (float*)alloc((size_t)2 * 17 * 4096 * 4);
    float* proto = (float*)alloc((size_t)2 * 16 * 17 * 4);
    float* W1T = (float*)alloc(16384 * 4);
    float* W2T = (float*)alloc(4096 * 4);
    float* W3T = (float*)alloc(1088 * 4);

    init_kernel<<<(2 * N + 255) / 256, 256, 0, stream>>>(rnk, out, 2 * N);
    transpose_kernel<<<(21568 + 255) / 256, 256, 0, stream>>>(W1, W2, W3, W1T, W2T, W3T);
    dim3 gprep((N + 255) / 256, 2);
    prep_kernel<<<gprep, 256, 0, stream>>>(pc_xyz, scales, rots, opacity, viewmat, intrins,
                                           keys, pu, pv, phA, phC, pnB, pop, N);
    dim3 grank((N + 255) / 256, (N + RANK_CHUNK - 1) / RANK_CHUNK, 2);
    rank_kernel<<<grank, 256, 0, stream>>>(keys, rnk, N);
    scatter_kernel<<<gprep, 256, 0, stream>>>(rnk, pu, pv, phA, phC, pnB, pop, voxel_feats, rec, N);
    dim3 gsplat(P_PIX / 256, NC, 2);
    splat_kernel<<<gsplat, 256, 0, stream>>>(rec, part, N);
    dim3 gtp(P_PIX / 256, 2);
    tpref_kernel<<<gtp, 256, 0, stream>>>(part, tpref);
    combine_kernel<<<(2 * 17 * P_PIX + 255) / 256, 256, 0, stream>>>(part, tpref, fmap);
    mlp_kernel<<<1024, 256, 0, stream>>>(sam_embd, sam_features, W1T, b1, g1, be1,
                                         W2T, b2, g2, be2, W3T, b3, sed, ldf);
    dim3 gproto(16, 2);
    proto_kernel<<<gproto, 256, 0, stream>>>(sam_masks, ldf, proto);
    bce_kernel<<<(2 * 16 * P_PIX) / 256, 256, 0, stream>>>(sam_masks, proto, fmap, out);
    l1_kernel<<<(2 * P_PIX + 255) / 256, 256, 0, stream>>>(fmap, sed, out);
}